// Round 9
// baseline (170.243 us; speedup 1.0000x reference)
//
#include <hip/hip_runtime.h>
#include <hip/hip_fp16.h>

// Deformable Conv2d — MI355X, round 9
// vs round 8: 1024-thread blocks, ONE 32-pixel tile per thread (was two).
// Halved per-wave work + ~45-60 VGPR keeps us under the 64-VGPR cliff so
// 2 blocks x 16 waves = 32 waves/CU (8/SIMD, HW max) can be resident —
// attacking the latency-bound regime (no pipe >50% in R6/R8). 13-row LDS
// window shared by 2 output rows; burst/weight loads issued before staging.

#define KSZ 3
#define PAD 1

static constexpr int B   = 4;
static constexpr int Cin = 64;
static constexpr int H   = 256;
static constexpr int W   = 256;
static constexpr int G   = 8;
static constexpr int OC  = 64;
static constexpr int KK  = KSZ * KSZ;  // 9
static constexpr int Cpg = Cin / G;    // 8
static constexpr int OPG = OC / G;     // 8
static constexpr int HW  = H * W;
static constexpr int NXCD = 8;

static constexpr int WROWS  = 13;      // window rows: h_base-5 .. h_base+7
static constexpr int WUP    = 5;
static constexpr int WPITCH = 257;     // 16B slots/row

typedef _Float16 f16x8  __attribute__((ext_vector_type(8)));
typedef float    f32x16 __attribute__((ext_vector_type(16)));

union U4H {
    uint4 u;
    __half2 h2[4];
    _Float16 h[8];
    f16x8 v;
};

// ---- transpose: x [B,Cin,H,W] f32 -> xt [B,G,H,W,Cpg] fp16 (16B/pixel) ----
__global__ __launch_bounds__(256) void transpose_kernel(
    const float* __restrict__ x, uint4* __restrict__ xt)
{
    const int h = blockIdx.x, g = blockIdx.y, b = blockIdx.z;
    const int w = threadIdx.x;
    const int pix = h * W + w;
    const float* src = x + (size_t)(b * Cin + g * Cpg) * HW + pix;
    U4H v;
#pragma unroll
    for (int c = 0; c < 8; ++c) v.h[c] = (_Float16)src[(size_t)c * HW];
    xt[(size_t)(b * G + g) * HW + pix] = v.u;
}

// ---- main kernel: 1024 threads, 2 output rows/block, 1 tile/thread ----
__global__ __launch_bounds__(1024) void dcn_kernel(
    const uint4* __restrict__ xt,
    const float* __restrict__ offset,
    const float* __restrict__ mask,
    const float* __restrict__ weight,
    const float* __restrict__ bias,
    float* __restrict__ out)
{
    __shared__ uint4 win[WROWS * WPITCH];   // 53,456 B

    // XCD-chunked bijective swizzle over 4096 blocks (4096 % 8 == 0)
    const unsigned id = blockIdx.x;
    const unsigned wl = (id & (NXCD - 1)) * (gridDim.x / NXCD) + (id >> 3);
    const int p  = wl & (H / 2 - 1);          // row-pair index
    const int bg = wl >> 7;
    const int g  = bg & (G - 1);
    const int b  = bg >> 3;
    const int h_base = 2 * p;

    const int tid  = threadIdx.x;
    const int lane = tid & 63;
    const int wave = tid >> 6;                // 0..15
    const int row_sel = wave >> 3;            // 0 or 1 -> output row
    const int wv   = wave & 7;                // column tile within the row
    const int hi   = lane >> 5;               // tap parity in MFMA k dim
    const int lp   = lane & 31;               // A-row (out ch) / B-col (pixel)

    const int h  = h_base + row_sel;
    const int h0 = h_base - WUP;
    const int wq = wv * 32 + lp;              // this thread's pixel column

    const uint4* xb = xt + (size_t)(b * G + g) * HW;

    const float* offy = offset + (size_t)(b * 2 + 0) * (G * KK) * HW;
    const float* offx = offset + (size_t)(b * 2 + 1) * (G * KK) * HW;
    const float* mk   = mask + (size_t)b * (G * KK) * HW;

    // burst offset/mask loads first (global latency overlaps staging below)
    float dyv[5], dxv[5], msv[5];
    {
        const int pix = h * W + wq;
#pragma unroll
        for (int m = 0; m < 5; ++m) {
            const int t  = 2 * m + hi;
            const int tt = (t > 8) ? 8 : t;
            const int idx0 = G * KK - 1 - (g * KK + tt);   // flipped tap axis
            dyv[m] = offy[(size_t)idx0 * HW + pix];
            dxv[m] = offx[(size_t)idx0 * HW + pix];
            const float mv = mk[(size_t)(g * KK + tt) * HW + pix];
            float s = 1.0f / (1.0f + __expf(-mv));
            msv[m] = (t <= 8) ? s : 0.0f;
        }
    }

    // A-fragments: weights, A[row=d][k=hi*8+c] -> tap 2m+hi, channel c.
    f16x8 afrag[5];
#pragma unroll
    for (int m = 0; m < 5; ++m) {
        f16x8 a = {};
        const int t = 2 * m + hi;
        if (lp < OPG && t < KK) {
            const float* wp = weight + (size_t)(g * OPG + lp) * Cpg * KK + t;
#pragma unroll
            for (int c = 0; c < 8; ++c) a[c] = (_Float16)wp[c * KK];
        }
        afrag[m] = a;
    }

    // ---- stage the 13-row window (rows pre-clamped) ----
#pragma unroll
    for (int it = 0; it < 4; ++it) {
        const int k = it * 1024 + tid;
        if (k < WROWS * 256) {
            const int i   = k >> 8;
            const int col = k & 255;
            const int wr  = min(max(h0 + i, 0), H - 1);
            win[i * WPITCH + col] = xb[wr * W + col];
        }
    }

    __syncthreads();   // window ready

    // one tap: bilinear blend of 4 corners from the LDS window
    auto sample = [&](int t, float dy, float dx, float msig) -> f16x8 {
        const int tt = (t > 8) ? 8 : t;
        const int ki = (tt >= 3) + (tt >= 6);
        const int kj = tt - 3 * ki;

        const float py = (float)(h - PAD + ki) + dy;
        const float px = (float)(wq - PAD + kj) + dx;
        const float y0f = floorf(py), x0f = floorf(px);
        const float wy = py - y0f, wx = px - x0f;
        const int y0 = (int)y0f, x0 = (int)x0f;
        const bool vy0 = (y0 >= 0) & (y0 < H), vy1 = (y0 + 1 >= 0) & (y0 + 1 < H);
        const bool vx0 = (x0 >= 0) & (x0 < W), vx1 = (x0 + 1 >= 0) & (x0 + 1 < W);

        const float u   = vy0 ? (1.f - wy) * msig : 0.f;
        const float v   = vy1 ? wy * msig : 0.f;
        const float cx0 = vx0 ? (1.f - wx) : 0.f;
        const float cx1 = vx1 ? wx : 0.f;

        const int iy0 = y0 - h0;
        const int iy1 = iy0 + 1;
        const int i0 = min(max(iy0, 0), WROWS - 1);
        const int i1 = min(max(iy1, 0), WROWS - 1);
        const int xc0 = min(max(x0, 0), W - 1);
        const int xc1 = min(max(x0 + 1, 0), W - 1);

        uint4 v00 = win[i0 * WPITCH + xc0];
        uint4 v01 = win[i0 * WPITCH + xc1];
        uint4 v10 = win[i1 * WPITCH + xc0];
        uint4 v11 = win[i1 * WPITCH + xc1];

        const bool bad = (vy0 & ((unsigned)iy0 > (unsigned)(WROWS - 1))) |
                         (vy1 & ((unsigned)iy1 > (unsigned)(WROWS - 1)));
        if (__builtin_expect(__any((int)bad), 0)) {   // |dy| > ~4 : p ~ 3e-5
            if (bad) {
                const int yc0 = min(max(y0, 0), H - 1);
                const int yc1 = min(max(y0 + 1, 0), H - 1);
                v00 = xb[yc0 * W + xc0];
                v01 = xb[yc0 * W + xc1];
                v10 = xb[yc1 * W + xc0];
                v11 = xb[yc1 * W + xc1];
            }
        }

        const float w00 = u * cx0, w01 = u * cx1, w10 = v * cx0, w11 = v * cx1;
        U4H a, bq, c, d; a.u = v00; bq.u = v01; c.u = v10; d.u = v11;
        const __half2 hw00 = __float2half2_rn(w00);
        const __half2 hw01 = __float2half2_rn(w01);
        const __half2 hw10 = __float2half2_rn(w10);
        const __half2 hw11 = __float2half2_rn(w11);
        U4H s;
#pragma unroll
        for (int i = 0; i < 4; ++i)
            s.h2[i] = __hfma2(hw00, a.h2[i],
                      __hfma2(hw01, bq.h2[i],
                      __hfma2(hw10, c.h2[i],
                      __hmul2(hw11, d.h2[i]))));
        return s.v;
    };

    f32x16 acc = {};
#pragma unroll
    for (int m = 0; m < 5; ++m)
        acc = __builtin_amdgcn_mfma_f32_32x32x16_f16(
            afrag[m], sample(2 * m + hi, dyv[m], dxv[m], msv[m]), acc, 0, 0, 0);

    // C layout: col = lp (pixel), row = (reg&3) + 8*(reg>>2) + 4*hi.
    // Useful rows 0..7 -> out channel d = reg + 4*hi (regs 0..3).
#pragma unroll
    for (int r = 0; r < 4; ++r) {
        const int dd = r + 4 * hi;
        out[((size_t)b * OC + g * OPG + dd) * HW + h * W + wq] =
            acc[r] + bias[g * OPG + dd];
    }
}

extern "C" void kernel_launch(void* const* d_in, const int* in_sizes, int n_in,
                              void* d_out, int out_size, void* d_ws, size_t ws_size,
                              hipStream_t stream) {
    const float* x      = (const float*)d_in[0];
    const float* offset = (const float*)d_in[1];
    const float* mask   = (const float*)d_in[2];
    const float* weight = (const float*)d_in[3];
    const float* bias   = (const float*)d_in[4];
    float* out = (float*)d_out;
    uint4* xt  = (uint4*)d_ws;   // B*G*HW * 16B = 32 MiB

    dim3 tgrid(H, G, B);
    transpose_kernel<<<tgrid, dim3(256), 0, stream>>>(x, xt);
    dcn_kernel<<<dim3(B * G * H / 2), dim3(1024), 0, stream>>>(xt, offset, mask, weight, bias, out);
}

// Round 10
// 96.076 us; speedup vs baseline: 1.7720x; 1.7720x over previous
//
#include <hip/hip_runtime.h>
#include <hip/hip_fp16.h>

// Deformable Conv2d — MI355X, round 10
// vs rounds 6-9: occupancy experiments proved waves aren't the lever (12->32
// waves/CU left perf flat/worse); VALU instruction count is. Back to the R6
// structure (256 thr, 1 row/block, 12-row LDS window) with two VALU cuts:
//  (1) per-lane MFMA A-fragments precomputed once into d_ws -> dcn does 5
//      coalesced dwordx4 loads instead of 40 scalar loads + cvt + pack;
//  (2) wave-uniform __all(interior) fast path per tap skips all clamps and
//      validity cndmasks (margin-5 window makes it the >99% path).

#define KSZ 3
#define PAD 1

static constexpr int B   = 4;
static constexpr int Cin = 64;
static constexpr int H   = 256;
static constexpr int W   = 256;
static constexpr int G   = 8;
static constexpr int OC  = 64;
static constexpr int KK  = KSZ * KSZ;  // 9
static constexpr int Cpg = Cin / G;    // 8
static constexpr int OPG = OC / G;     // 8
static constexpr int HW  = H * W;
static constexpr int NXCD = 8;

static constexpr int WROWS  = 12;      // window rows: h-5 .. h+6
static constexpr int WUP    = 5;
static constexpr int WPITCH = 257;     // 16B slots/row

typedef _Float16 f16x8  __attribute__((ext_vector_type(8)));
typedef float    f32x16 __attribute__((ext_vector_type(16)));

union U4H {
    uint4 u;
    __half2 h2[4];
    _Float16 h[8];
    f16x8 v;
};

// ---- transpose: x [B,Cin,H,W] f32 -> xt [B,G,H,W,Cpg] fp16 (16B/pixel) ----
__global__ __launch_bounds__(256) void transpose_kernel(
    const float* __restrict__ x, uint4* __restrict__ xt)
{
    const int h = blockIdx.x, g = blockIdx.y, b = blockIdx.z;
    const int w = threadIdx.x;
    const int pix = h * W + w;
    const float* src = x + (size_t)(b * Cin + g * Cpg) * HW + pix;
    U4H v;
#pragma unroll
    for (int c = 0; c < 8; ++c) v.h[c] = (_Float16)src[(size_t)c * HW];
    xt[(size_t)(b * G + g) * HW + pix] = v.u;
}

// ---- prep: per-lane MFMA A-fragments, layout [g][m][lane] (40 KB) ----
__global__ __launch_bounds__(320) void prep_weights(
    const float* __restrict__ weight, uint4* __restrict__ wfrag)
{
    const int g    = blockIdx.x;
    const int tid  = threadIdx.x;     // 0..319
    const int m    = tid >> 6;        // 0..4
    const int lane = tid & 63;
    const int hi   = lane >> 5;
    const int lp   = lane & 31;
    const int t    = 2 * m + hi;
    U4H a;
#pragma unroll
    for (int c = 0; c < 8; ++c) {
        float v = 0.0f;
        if (lp < OPG && t < KK)
            v = weight[((size_t)(g * OPG + lp) * Cpg + c) * KK + t];
        a.h[c] = (_Float16)v;
    }
    wfrag[((size_t)g * 5 + m) * 64 + lane] = a.u;
}

// ---- main kernel: 256 threads, 1 output row/block ----
__global__ __launch_bounds__(256, 3) void dcn_kernel(
    const uint4* __restrict__ xt,
    const uint4* __restrict__ wfrag,
    const float* __restrict__ offset,
    const float* __restrict__ mask,
    const float* __restrict__ bias,
    float* __restrict__ out)
{
    __shared__ uint4 win[WROWS * WPITCH];   // 49,344 B -> 3 blocks/CU

    // XCD-chunked bijective swizzle (8192 blocks % 8 == 0)
    const unsigned id = blockIdx.x;
    const unsigned wl = (id & (NXCD - 1)) * (gridDim.x / NXCD) + (id >> 3);
    const int h  = wl & (H - 1);
    const int bg = wl >> 8;
    const int g  = bg & (G - 1);
    const int b  = bg >> 3;

    const int tid  = threadIdx.x;
    const int lane = tid & 63;
    const int wave = tid >> 6;
    const int hi   = lane >> 5;   // tap parity in MFMA k dim
    const int lp   = lane & 31;   // A-row (out ch) / B-col (pixel)

    const uint4* xb = xt + (size_t)(b * G + g) * HW;
    const int h0 = h - WUP;

    // ---- stage the 12-row window (rows pre-clamped) ----
#pragma unroll
    for (int i = 0; i < WROWS; ++i) {
        const int wr = min(max(h0 + i, 0), H - 1);
        win[i * WPITCH + tid] = xb[wr * W + tid];
    }

    // A-fragments: 5 coalesced dwordx4 loads (precomputed by prep_weights)
    f16x8 afrag[5];
    {
        const uint4* wf = wfrag + (size_t)g * 5 * 64 + lane;
#pragma unroll
        for (int m = 0; m < 5; ++m) {
            U4H tmp; tmp.u = wf[m * 64];
            afrag[m] = tmp.v;
        }
    }

    const float* offy = offset + (size_t)(b * 2 + 0) * (G * KK) * HW;
    const float* offx = offset + (size_t)(b * 2 + 1) * (G * KK) * HW;
    const float* mk   = mask + (size_t)b * (G * KK) * HW;

    // burst all offset/mask loads (sigmoid + tap-9 pad folded here)
    float dyv[2][5], dxv[2][5], msv[2][5];
#pragma unroll
    for (int tile = 0; tile < 2; ++tile) {
        const int wq  = wave * 64 + tile * 32 + lp;
        const int pix = h * W + wq;
#pragma unroll
        for (int m = 0; m < 5; ++m) {
            const int t  = 2 * m + hi;
            const int tt = (t > 8) ? 8 : t;
            const int idx0 = G * KK - 1 - (g * KK + tt);   // flipped tap axis
            dyv[tile][m] = offy[(size_t)idx0 * HW + pix];
            dxv[tile][m] = offx[(size_t)idx0 * HW + pix];
            const float mv = mk[(size_t)(g * KK + tt) * HW + pix];
            float s = 1.0f / (1.0f + __expf(-mv));
            msv[tile][m] = (t <= 8) ? s : 0.0f;
        }
    }

    __syncthreads();   // window ready

    // one tap: bilinear blend of 4 corners from the LDS window
    auto sample = [&](int t, int wq, float dy, float dx, float msig) -> f16x8 {
        const int tt = (t > 8) ? 8 : t;
        const int ki = (tt >= 3) + (tt >= 6);
        const int kj = tt - 3 * ki;

        const float py = (float)(h - PAD + ki) + dy;
        const float px = (float)(wq - PAD + kj) + dx;
        const float y0f = floorf(py), x0f = floorf(px);
        const float wy = py - y0f, wx = px - x0f;
        const int y0 = (int)y0f, x0 = (int)x0f;
        const int iy0 = y0 - h0, iy1 = iy0 + 1;

        float w00, w01, w10, w11;
        uint4 v00, v01, v10, v11;

        const bool ok = (y0 >= 0) & (y0 + 1 < H) & (x0 >= 0) & (x0 + 1 < W) &
                        ((unsigned)iy0 <= (unsigned)(WROWS - 2));
        if (__all((int)ok)) {
            // interior fast path: no clamps, no validity masks
            const float u = (1.f - wy) * msig, v = wy * msig;
            w00 = u * (1.f - wx); w01 = u * wx;
            w10 = v * (1.f - wx); w11 = v * wx;
            const int a0 = iy0 * WPITCH + x0;
            v00 = win[a0];          v01 = win[a0 + 1];
            v10 = win[a0 + WPITCH]; v11 = win[a0 + WPITCH + 1];
        } else {
            const bool vy0 = (y0 >= 0) & (y0 < H), vy1 = (y0 + 1 >= 0) & (y0 + 1 < H);
            const bool vx0 = (x0 >= 0) & (x0 < W), vx1 = (x0 + 1 >= 0) & (x0 + 1 < W);
            const float u   = vy0 ? (1.f - wy) * msig : 0.f;
            const float v   = vy1 ? wy * msig : 0.f;
            const float cx0 = vx0 ? (1.f - wx) : 0.f;
            const float cx1 = vx1 ? wx : 0.f;
            w00 = u * cx0; w01 = u * cx1; w10 = v * cx0; w11 = v * cx1;

            const int i0 = min(max(iy0, 0), WROWS - 1);
            const int i1 = min(max(iy1, 0), WROWS - 1);
            const int xc0 = min(max(x0, 0), W - 1);
            const int xc1 = min(max(x0 + 1, 0), W - 1);
            v00 = win[i0 * WPITCH + xc0];
            v01 = win[i0 * WPITCH + xc1];
            v10 = win[i1 * WPITCH + xc0];
            v11 = win[i1 * WPITCH + xc1];

            const bool bad = (vy0 & ((unsigned)iy0 > (unsigned)(WROWS - 1))) |
                             (vy1 & ((unsigned)iy1 > (unsigned)(WROWS - 1)));
            if (__builtin_expect(__any((int)bad), 0)) {   // |dy| > ~5
                if (bad) {
                    const int yc0 = min(max(y0, 0), H - 1);
                    const int yc1 = min(max(y0 + 1, 0), H - 1);
                    v00 = xb[yc0 * W + xc0];
                    v01 = xb[yc0 * W + xc1];
                    v10 = xb[yc1 * W + xc0];
                    v11 = xb[yc1 * W + xc1];
                }
            }
        }

        U4H a, bq, c, d; a.u = v00; bq.u = v01; c.u = v10; d.u = v11;
        const __half2 hw00 = __float2half2_rn(w00);
        const __half2 hw01 = __float2half2_rn(w01);
        const __half2 hw10 = __float2half2_rn(w10);
        const __half2 hw11 = __float2half2_rn(w11);
        U4H s;
#pragma unroll
        for (int i = 0; i < 4; ++i)
            s.h2[i] = __hfma2(hw00, a.h2[i],
                      __hfma2(hw01, bq.h2[i],
                      __hfma2(hw10, c.h2[i],
                      __hmul2(hw11, d.h2[i]))));
        return s.v;
    };

    f32x16 acc0 = {};
    f32x16 acc1 = {};
    {
        const int wq = wave * 64 + lp;
#pragma unroll
        for (int m = 0; m < 5; ++m)
            acc0 = __builtin_amdgcn_mfma_f32_32x32x16_f16(
                afrag[m], sample(2 * m + hi, wq, dyv[0][m], dxv[0][m], msv[0][m]), acc0, 0, 0, 0);
    }
    {
        const int wq = wave * 64 + 32 + lp;
#pragma unroll
        for (int m = 0; m < 5; ++m)
            acc1 = __builtin_amdgcn_mfma_f32_32x32x16_f16(
                afrag[m], sample(2 * m + hi, wq, dyv[1][m], dxv[1][m], msv[1][m]), acc1, 0, 0, 0);
    }

    // C layout: col = lp (pixel), row = (reg&3) + 8*(reg>>2) + 4*hi.
    // Useful rows 0..7 -> out channel d = reg + 4*hi (regs 0..3).
#pragma unroll
    for (int tile = 0; tile < 2; ++tile) {
        const int wq = wave * 64 + tile * 32 + lp;
#pragma unroll
        for (int r = 0; r < 4; ++r) {
            const int dd = r + 4 * hi;
            const float v = (tile == 0 ? acc0[r] : acc1[r]) + bias[g * OPG + dd];
            out[((size_t)b * OC + g * OPG + dd) * HW + h * W + wq] = v;
        }
    }
}

extern "C" void kernel_launch(void* const* d_in, const int* in_sizes, int n_in,
                              void* d_out, int out_size, void* d_ws, size_t ws_size,
                              hipStream_t stream) {
    const float* x      = (const float*)d_in[0];
    const float* offset = (const float*)d_in[1];
    const float* mask   = (const float*)d_in[2];
    const float* weight = (const float*)d_in[3];
    const float* bias   = (const float*)d_in[4];
    float* out = (float*)d_out;

    uint4* xt    = (uint4*)d_ws;                          // 32 MiB
    uint4* wfrag = (uint4*)((char*)d_ws + (size_t)B * G * HW * 16);  // 40 KiB

    dim3 tgrid(H, G, B);
    transpose_kernel<<<tgrid, dim3(256), 0, stream>>>(x, xt);
    prep_weights<<<dim3(G), dim3(320), 0, stream>>>(weight, wfrag);
    dcn_kernel<<<dim3(B * G * H), dim3(256), 0, stream>>>(xt, wfrag, offset, mask, bias, out);
}